// Round 1
// baseline (744.707 us; speedup 1.0000x reference)
//
#include <hip/hip_runtime.h>
#include <stdint.h>

// ---------------------------------------------------------------------------
// TimeAwareIMULSTMEncoder on MI355X (gfx950)
// B=32,T1=40 -> N=1280 rows; L=50; D=6; H=128; 4H=512; LSTM_IN=64; OUT=256
// Pipeline:
//   k_prep    : transpose+bf16-cast all Wih/Whh -> [2][512][K] (n-major)
//   k_inproj  : [imu,t,rate] @ W_in + b, relu -> act0 [64000][64] bf16
//   per layer : k_xg_gemm (MFMA bf16, xg = X@Wih + bih+bhh -> bf16 [dir][64000][512])
//               k_scan    (persistent per-16-seq block; Whh^T frags in VGPRs;
//                          gates in-register; c fp32 regs; h bf16 dbl-buffered LDS)
//   k_agg     : mean/max/final over L -> agg [1280][768] f32
//   k_head1   : agg @ Wout1 + bout1 (fp32) -> h1 [1280][512]
//   k_head2   : LayerNorm+relu+@Wout2+bout2 (fp32) -> out [1280][256]
// ---------------------------------------------------------------------------

typedef unsigned short ushort_t;
typedef short short8 __attribute__((ext_vector_type(8)));     // 8 bf16 (4 VGPRs)
typedef float float4v __attribute__((ext_vector_type(4)));    // MFMA acc

#define DEV_INLINE __device__ __forceinline__

DEV_INLINE ushort_t f2bf(float f) {                 // RNE f32 -> bf16 bits
  union { float f; unsigned u; } v; v.f = f;
  unsigned r = v.u + 0x7fffu + ((v.u >> 16) & 1u);
  return (ushort_t)(r >> 16);
}
DEV_INLINE float bf2f(ushort_t s) {
  union { unsigned u; float f; } v; v.u = ((unsigned)s) << 16;
  return v.f;
}
DEV_INLINE float sigmoidf_(float x) {
  return __builtin_amdgcn_rcpf(1.0f + __expf(-x));
}
DEV_INLINE float tanhf_(float x) {                  // 1 - 2/(1+e^{2x}); safe at +-inf
  return 1.0f - 2.0f * __builtin_amdgcn_rcpf(1.0f + __expf(2.0f * x));
}

// --------------------------- weight prep -----------------------------------
// WT arena layout (elements): Wih0[2*512*64] | Wih1[2*512*256] | Wih2[2*512*256]
//                           | Whh0[2*512*128] | Whh1[2*512*128] | Whh2[2*512*128]
__global__ __launch_bounds__(256) void k_prep(
    const float* __restrict__ Wih0, const float* __restrict__ Wih1,
    const float* __restrict__ Wih2, const float* __restrict__ Whh0,
    const float* __restrict__ Whh1, const float* __restrict__ Whh2,
    ushort_t* __restrict__ WT)
{
  int idx = blockIdx.x * 256 + threadIdx.x;
  const float* src; int K, klog, base;
  if      (idx < 65536)  { src = Wih0; K = 64;  klog = 6; base = 0; }
  else if (idx < 327680) { src = Wih1; K = 256; klog = 8; base = 65536; }
  else if (idx < 589824) { src = Wih2; K = 256; klog = 8; base = 327680; }
  else if (idx < 720896) { src = Whh0; K = 128; klog = 7; base = 589824; }
  else if (idx < 851968) { src = Whh1; K = 128; klog = 7; base = 720896; }
  else if (idx < 983040) { src = Whh2; K = 128; klog = 7; base = 851968; }
  else return;
  int li = idx - base;
  int k = li & (K - 1);
  int nd = li >> klog;
  int n = nd & 511, d = nd >> 9;
  WT[idx] = f2bf(src[(size_t)(d * K + k) * 512 + n]);
}

// --------------------------- input projection ------------------------------
__global__ __launch_bounds__(256) void k_inproj(
    const float* __restrict__ imu, const float* __restrict__ W_in,
    const float* __restrict__ b_in, ushort_t* __restrict__ act0)
{
  int idx = blockIdx.x * 256 + threadIdx.x;   // 64000*64 exactly
  int j = idx & 63, r = idx >> 6;
  int l = r % 50;
  const float* x = imu + (size_t)r * 6;
  float acc = b_in[j];
#pragma unroll
  for (int d = 0; d < 6; d++) acc += x[d] * W_in[d * 64 + j];
  acc += (l * (1.0f / 49.0f)) * W_in[6 * 64 + j] + W_in[7 * 64 + j]; // t, rate=1
  act0[idx] = f2bf(fmaxf(acc, 0.0f));
}

// --------------------------- xg GEMM (bf16 MFMA) ---------------------------
// xg[dirSlot][m][n] = X[m][:] @ Wih[dir][:][n] + bih[dir][n] + bhh[dir][n]
template <int K>
__global__ __launch_bounds__(256, 2) void k_xg_gemm(
    const ushort_t* __restrict__ X,    // [64000][K] bf16
    const ushort_t* __restrict__ WT,   // [2][512][K] bf16 (n-major)
    const float* __restrict__ bih, const float* __restrict__ bhh, // [2][512]
    ushort_t* __restrict__ xg,         // [gridDim.z][64000][512] bf16
    int dirBase)
{
  constexpr int LDA = 72;              // 64 + 8 pad: 144 B row, 16B-aligned, 2-way-free
  __shared__ ushort_t As[128 * LDA];
  __shared__ ushort_t Bs[128 * LDA];
  const int dir = blockIdx.z + dirBase;
  const int m0 = blockIdx.x * 128;
  const int n0 = blockIdx.y * 128;
  const int tid = threadIdx.x;
  const int wave = tid >> 6, lane = tid & 63;
  const int cl = lane & 15, quad = lane >> 4;
  const int wm = (wave & 1) * 64, wn = (wave >> 1) * 64;
  const ushort_t* Wd = WT + ((size_t)dir * 512 + n0) * K;

  float4v acc[4][4];
#pragma unroll
  for (int i = 0; i < 4; i++)
#pragma unroll
    for (int j = 0; j < 4; j++) acc[i][j] = float4v{0.f, 0.f, 0.f, 0.f};

  const int lr = tid >> 3;             // 0..31
  const int lc = (tid & 7) * 8;        // 0..56

  for (int kb = 0; kb < K; kb += 64) {
#pragma unroll
    for (int it = 0; it < 4; it++) {
      int row = lr + it * 32;
      *(uint4*)(&As[row * LDA + lc]) =
          *(const uint4*)(X + (size_t)(m0 + row) * K + kb + lc);
      *(uint4*)(&Bs[row * LDA + lc]) =
          *(const uint4*)(Wd + (size_t)row * K + kb + lc);
    }
    __syncthreads();
#pragma unroll
    for (int ks = 0; ks < 2; ks++) {
      short8 af[4], bf[4];
#pragma unroll
      for (int i = 0; i < 4; i++)
        af[i] = *(const short8*)(&As[(wm + i * 16 + cl) * LDA + ks * 32 + quad * 8]);
#pragma unroll
      for (int j = 0; j < 4; j++)
        bf[j] = *(const short8*)(&Bs[(wn + j * 16 + cl) * LDA + ks * 32 + quad * 8]);
#pragma unroll
      for (int i = 0; i < 4; i++)
#pragma unroll
        for (int j = 0; j < 4; j++)
          acc[i][j] = __builtin_amdgcn_mfma_f32_16x16x32_bf16(af[i], bf[j], acc[i][j], 0, 0, 0);
    }
    __syncthreads();
  }

  ushort_t* out = xg + (size_t)blockIdx.z * (64000ull * 512);
  const float* b1 = bih + dir * 512 + n0;
  const float* b2 = bhh + dir * 512 + n0;
#pragma unroll
  for (int j = 0; j < 4; j++) {
    int col = wn + j * 16 + cl;
    float bias = b1[col] + b2[col];
#pragma unroll
    for (int i = 0; i < 4; i++) {
#pragma unroll
      for (int r = 0; r < 4; r++) {
        int row = wm + i * 16 + quad * 4 + r;     // D: row=quad*4+reg, col=lane&15
        out[(size_t)(m0 + row) * 512 + n0 + col] = f2bf(acc[i][j][r] + bias);
      }
    }
  }
}

// --------------------------- LSTM scan -------------------------------------
// One block = 16 sequences of one direction, all 50 steps.
// Whh^T fragments live in VGPRs (32 frags = 128 VGPRs). Wave w owns gate cols
// [32w,32w+32): for gate g, u in {0,1}, the MFMA N-tile covers cols
// g*128 + 32w + 16u + (lane&15)  -> every lane holds i,f,g,o for its (seq,col)
// in its own accumulators; pointwise is fully in-register. c stays in fp32
// registers; h is bf16 in double-buffered LDS (one barrier per step).
__global__ __launch_bounds__(256, 1) void k_scan(
    const ushort_t* __restrict__ xg,    // [gridDim.y][64000][512] bf16
    const ushort_t* __restrict__ WhhT,  // [2][512][128] bf16
    ushort_t* __restrict__ Y,           // [64000][256] bf16
    int dirBase)
{
  const int dir = blockIdx.y + dirBase;
  const int s0 = blockIdx.x * 16;
  const int tid = threadIdx.x;
  const int wave = tid >> 6, lane = tid & 63;
  const int cl = lane & 15, quad = lane >> 4;
  __shared__ ushort_t hbuf[2][16][136];           // 8.7 KiB, +8 pad (2-way-free reads)

  short8 Bf[4][2][4];                             // [gate][u][kt]
  const ushort_t* WTd = WhhT + (size_t)dir * (512 * 128);
#pragma unroll
  for (int g = 0; g < 4; g++)
#pragma unroll
    for (int u = 0; u < 2; u++) {
      int n = g * 128 + wave * 32 + u * 16 + cl;
#pragma unroll
      for (int kt = 0; kt < 4; kt++)
        Bf[g][u][kt] = *(const short8*)(WTd + n * 128 + kt * 32 + quad * 8);
    }

  float cst[2][4];
#pragma unroll
  for (int u = 0; u < 2; u++)
#pragma unroll
    for (int r = 0; r < 4; r++) cst[u][r] = 0.0f;

  for (int i = tid; i < 2 * 16 * 136; i += 256) ((ushort_t*)hbuf)[i] = 0;
  __syncthreads();

  const ushort_t* xgp = xg + (size_t)blockIdx.y * (64000ull * 512);

  for (int step = 0; step < 50; step++) {
    const int t = dir ? (49 - step) : step;
    const int cur = step & 1;

    // prefetch this step's input-side gates (independent of h -> overlaps MFMA)
    float xv[4][2][4];
#pragma unroll
    for (int g = 0; g < 4; g++)
#pragma unroll
      for (int u = 0; u < 2; u++) {
        int col = g * 128 + wave * 32 + u * 16 + cl;
#pragma unroll
        for (int r = 0; r < 4; r++) {
          size_t row = (size_t)(s0 + quad * 4 + r) * 50 + t;
          xv[g][u][r] = bf2f(xgp[row * 512 + col]);
        }
      }

    short8 Af[4];
#pragma unroll
    for (int kt = 0; kt < 4; kt++)                // A: m=lane&15, k=quad*8+j
      Af[kt] = *(const short8*)(&hbuf[cur][cl][kt * 32 + quad * 8]);

    float4v acc[4][2];
#pragma unroll
    for (int g = 0; g < 4; g++)
#pragma unroll
      for (int u = 0; u < 2; u++) acc[g][u] = float4v{0.f, 0.f, 0.f, 0.f};
#pragma unroll
    for (int kt = 0; kt < 4; kt++)
#pragma unroll
      for (int g = 0; g < 4; g++)
#pragma unroll
        for (int u = 0; u < 2; u++)
          acc[g][u] = __builtin_amdgcn_mfma_f32_16x16x32_bf16(Af[kt], Bf[g][u][kt], acc[g][u], 0, 0, 0);

#pragma unroll
    for (int u = 0; u < 2; u++) {
      int j = wave * 32 + u * 16 + cl;
#pragma unroll
      for (int r = 0; r < 4; r++) {
        float gi = acc[0][u][r] + xv[0][u][r];
        float gf = acc[1][u][r] + xv[1][u][r];
        float gg = acc[2][u][r] + xv[2][u][r];
        float go = acc[3][u][r] + xv[3][u][r];
        float ii = sigmoidf_(gi);
        float ff = sigmoidf_(gf);
        float gc = tanhf_(gg);
        float oo = sigmoidf_(go);
        float c = ff * cst[u][r] + ii * gc;
        cst[u][r] = c;
        float h = oo * tanhf_(c);
        ushort_t hb = f2bf(h);
        int s = quad * 4 + r;
        hbuf[cur ^ 1][s][j] = hb;
        Y[((size_t)(s0 + s) * 50 + t) * 256 + dir * 128 + j] = hb;
      }
    }
    __syncthreads();
  }
}

// --------------------------- aggregation -----------------------------------
__global__ __launch_bounds__(256) void k_agg(const ushort_t* __restrict__ Y2,
                                             float* __restrict__ agg)
{
  int n = blockIdx.x, c = threadIdx.x;
  const ushort_t* base = Y2 + (size_t)n * 50 * 256;
  float mean = 0.0f, mx = -3.0e38f;
  for (int l = 0; l < 50; l++) {
    float v = bf2f(base[l * 256 + c]);
    mean += v;
    mx = fmaxf(mx, v);
  }
  float* a = agg + (size_t)n * 768;
  a[c] = mean * (1.0f / 50.0f);
  a[256 + c] = mx;
  a[512 + c] = (c < 128) ? bf2f(base[49 * 256 + c])   // fwd h_n at t=L-1
                         : bf2f(base[c]);             // bwd h_n at t=0
}

// --------------------------- head: GEMM1 (fp32) -----------------------------
__global__ __launch_bounds__(256) void k_head1(
    const float* __restrict__ agg, const float* __restrict__ W1,
    const float* __restrict__ b1, float* __restrict__ h1)
{
  __shared__ float aggS[16][772];
  const int n0 = blockIdx.x * 16;
  const int c0 = blockIdx.y * 128;
  const int tid = threadIdx.x;
  for (int i = tid; i < 16 * 192; i += 256) {
    int row = i / 192, c4 = i % 192;
    *(float4v*)(&aggS[row][c4 * 4]) =
        *(const float4v*)(agg + (size_t)(n0 + row) * 768 + c4 * 4);
  }
  __syncthreads();
  const int cq = tid & 31;          // cols c0 + cq*4 .. +3
  const int rp = tid >> 5;          // rows rp*2, rp*2+1
  float acc0[4] = {0.f, 0.f, 0.f, 0.f}, acc1[4] = {0.f, 0.f, 0.f, 0.f};
#pragma unroll 4
  for (int k = 0; k < 768; k++) {
    float4v w = *(const float4v*)(W1 + (size_t)k * 512 + c0 + cq * 4);
    float a0 = aggS[rp * 2][k], a1 = aggS[rp * 2 + 1][k];
#pragma unroll
    for (int q = 0; q < 4; q++) { acc0[q] += a0 * w[q]; acc1[q] += a1 * w[q]; }
  }
#pragma unroll
  for (int q = 0; q < 4; q++) {
    int col = c0 + cq * 4 + q;
    float bb = b1[col];
    h1[(size_t)(n0 + rp * 2) * 512 + col] = acc0[q] + bb;
    h1[(size_t)(n0 + rp * 2 + 1) * 512 + col] = acc1[q] + bb;
  }
}

// --------------------------- head: LN + relu + GEMM2 (fp32) -----------------
__global__ __launch_bounds__(256) void k_head2(
    const float* __restrict__ h1, const float* __restrict__ ln_g,
    const float* __restrict__ ln_b, const float* __restrict__ W2,
    const float* __restrict__ b2, float* __restrict__ out)
{
  __shared__ float hnS[8][516];
  const int n0 = blockIdx.x * 8;
  const int tid = threadIdx.x;
  const int row = tid >> 5, li = tid & 31;
  const float* hr = h1 + (size_t)(n0 + row) * 512;
  float sum = 0.f, sq = 0.f;
  float v[16];
#pragma unroll
  for (int j = 0; j < 16; j++) {
    v[j] = hr[li + 32 * j];
    sum += v[j]; sq += v[j] * v[j];
  }
#pragma unroll
  for (int m = 1; m <= 16; m <<= 1) {
    sum += __shfl_xor(sum, m);
    sq  += __shfl_xor(sq, m);
  }
  float mu = sum * (1.0f / 512.0f);
  float var = sq * (1.0f / 512.0f) - mu * mu;
  float rs = rsqrtf(var + 1e-5f);
#pragma unroll
  for (int j = 0; j < 16; j++) {
    int col = li + 32 * j;
    float y = (v[j] - mu) * rs * ln_g[col] + ln_b[col];
    hnS[row][col] = fmaxf(y, 0.0f);
  }
  __syncthreads();
  const int cq = tid & 63, rp = tid >> 6;   // cols cq*4..+3; rows rp*2, rp*2+1
  float acc0[4] = {0.f, 0.f, 0.f, 0.f}, acc1[4] = {0.f, 0.f, 0.f, 0.f};
#pragma unroll 4
  for (int k = 0; k < 512; k++) {
    float4v w = *(const float4v*)(W2 + (size_t)k * 256 + cq * 4);
    float a0 = hnS[rp * 2][k], a1 = hnS[rp * 2 + 1][k];
#pragma unroll
    for (int q = 0; q < 4; q++) { acc0[q] += a0 * w[q]; acc1[q] += a1 * w[q]; }
  }
#pragma unroll
  for (int q = 0; q < 4; q++) {
    int col = cq * 4 + q;
    float bb = b2[col];
    out[(size_t)(n0 + rp * 2) * 256 + col] = acc0[q] + bb;
    out[(size_t)(n0 + rp * 2 + 1) * 256 + col] = acc1[q] + bb;
  }
}

// --------------------------- launcher --------------------------------------
extern "C" void kernel_launch(void* const* d_in, const int* in_sizes, int n_in,
                              void* d_out, int out_size, void* d_ws, size_t ws_size,
                              hipStream_t stream)
{
  (void)in_sizes; (void)n_in; (void)out_size;
  const float* imu   = (const float*)d_in[0];
  const float* W_in  = (const float*)d_in[1];
  const float* b_in  = (const float*)d_in[2];
  const float* Wih0  = (const float*)d_in[3];
  const float* Whh0  = (const float*)d_in[4];
  const float* bih0  = (const float*)d_in[5];
  const float* bhh0  = (const float*)d_in[6];
  const float* Wih1  = (const float*)d_in[7];
  const float* Whh1  = (const float*)d_in[8];
  const float* bih1  = (const float*)d_in[9];
  const float* bhh1  = (const float*)d_in[10];
  const float* Wih2  = (const float*)d_in[11];
  const float* Whh2  = (const float*)d_in[12];
  const float* bih2  = (const float*)d_in[13];
  const float* bhh2  = (const float*)d_in[14];
  const float* Wout1 = (const float*)d_in[15];
  const float* bout1 = (const float*)d_in[16];
  const float* ln_g  = (const float*)d_in[17];
  const float* ln_b  = (const float*)d_in[18];
  const float* Wout2 = (const float*)d_in[19];
  const float* bout2 = (const float*)d_in[20];
  float* out = (float*)d_out;
  char* ws = (char*)d_ws;

  // ws layout (bytes)
  const size_t ACT0_OFF = 0;                      // 8,192,000  (64000*64*2)
  const size_t YA_OFF   = 8192000;                // 32,768,000 (64000*256*2)
  const size_t YB_OFF   = 40960000;               // 32,768,000
  const size_t XG_OFF   = 73728000;               // 131,072,000 (both) / 65,536,000 (serial)
  const size_t XG_BOTH  = 131072000, XG_SER = 65536000;
  const size_t WT_SZ    = 1966080;                // 983,040 bf16 elems
  const bool both = ws_size >= XG_OFF + XG_BOTH + WT_SZ;
  const size_t WT_OFF = XG_OFF + (both ? XG_BOTH : XG_SER);

  ushort_t* act0 = (ushort_t*)(ws + ACT0_OFF);
  ushort_t* Ya   = (ushort_t*)(ws + YA_OFF);
  ushort_t* Yb   = (ushort_t*)(ws + YB_OFF);
  ushort_t* xg   = (ushort_t*)(ws + XG_OFF);
  ushort_t* WT   = (ushort_t*)(ws + WT_OFF);
  float* agg = (float*)(ws + 0);                  // reuses act0 region (dead by then)
  float* h1  = (float*)(ws + 4194304);

  ushort_t* WT_ih0 = WT + 0;
  ushort_t* WT_ih1 = WT + 65536;
  ushort_t* WT_ih2 = WT + 327680;
  ushort_t* WT_hh0 = WT + 589824;
  ushort_t* WT_hh1 = WT + 720896;
  ushort_t* WT_hh2 = WT + 851968;

  k_prep<<<3840, 256, 0, stream>>>(Wih0, Wih1, Wih2, Whh0, Whh1, Whh2, WT);
  k_inproj<<<16000, 256, 0, stream>>>(imu, W_in, b_in, act0);

  const int nPass = both ? 1 : 2;
  const int gz = both ? 2 : 1;

  const ushort_t* Xs[3]   = {act0, Ya, Yb};
  ushort_t* Ys[3]         = {Ya, Yb, Ya};
  const ushort_t* WTih[3] = {WT_ih0, WT_ih1, WT_ih2};
  const ushort_t* WThh[3] = {WT_hh0, WT_hh1, WT_hh2};
  const float* bihs[3]    = {bih0, bih1, bih2};
  const float* bhhs[3]    = {bhh0, bhh1, bhh2};

  for (int layer = 0; layer < 3; layer++) {
    for (int p = 0; p < nPass; p++) {
      int dirBase = both ? 0 : p;
      if (layer == 0)
        k_xg_gemm<64><<<dim3(500, 4, gz), 256, 0, stream>>>(
            Xs[0], WTih[0], bihs[0], bhhs[0], xg, dirBase);
      else
        k_xg_gemm<256><<<dim3(500, 4, gz), 256, 0, stream>>>(
            Xs[layer], WTih[layer], bihs[layer], bhhs[layer], xg, dirBase);
      k_scan<<<dim3(80, gz), 256, 0, stream>>>(xg, WThh[layer], Ys[layer], dirBase);
    }
  }

  k_agg<<<1280, 256, 0, stream>>>(Ya, agg);
  k_head1<<<dim3(80, 4), 256, 0, stream>>>(agg, Wout1, bout1, h1);
  k_head2<<<160, 256, 0, stream>>>(h1, ln_g, ln_b, Wout2, bout2, out);
}